// Round 9
// baseline (400.929 us; speedup 1.0000x reference)
//
#include <hip/hip_runtime.h>
#include <hip/hip_fp16.h>
#include <math.h>

#define BATCH 8
#define CIN   256
#define COUT  256
#define HH    64
#define WW    64
#define K2    9
#define CKTOT (CIN*K2)       // 2304
#define NPIX  (HH*WW)        // 4096
#define PB    16             // positions per block (quarter row; same b,y)
#define CCH   32             // channels per chunk
#define NCH   (CIN/CCH)      // 8 chunks
#define ROWBLK 40            // 16B-blocks per smp row (36 used + pad; XOR stays < 40)
#define INV_STRIDE 0.125f

typedef __attribute__((ext_vector_type(8))) short bf16x8;
typedef __attribute__((ext_vector_type(4))) float f32x4;

union Pack16 { uint4 u; bf16x8 v; };

__device__ __forceinline__ unsigned bf16rne(float f) {
    union { float f; unsigned u; } a; a.f = f;
    return (a.u + 0x7FFFu + ((a.u >> 16) & 1u)) >> 16;
}
__device__ __forceinline__ float bflo(unsigned u) {
    union { unsigned u; float f; } a; a.u = u << 16; return a.f;
}
__device__ __forceinline__ float bfhi(unsigned u) {
    union { unsigned u; float f; } a; a.u = u & 0xFFFF0000u; return a.f;
}

// ---- Kernel P (fused prep): blocks 0..2047 transpose x quarter-rows to NHWC bf16;
//      blocks 2048..2303 relayout w[o][c*9+kk] -> wbf[o][kk*256+c] bf16 ----
__global__ __launch_bounds__(256) void prep(const float* __restrict__ x,
                                            const float* __restrict__ w,
                                            ushort* __restrict__ xt,
                                            ushort* __restrict__ wbf) {
    __shared__ ushort shm[16 * (CIN + 2)];       // 8.25 KB (convert uses first 2304)
    const int bid = blockIdx.x;
    const int tid = threadIdx.x;
    if (bid < 2048) {
        // transpose: quarter-row (16 px) of (b,y)
        const int by = bid >> 2;
        const int q  = bid & 3;
        const float* __restrict__ xp = x + (size_t)(by >> 6) * CIN * NPIX
                                         + (size_t)(by & 63) * WW + q * 16;
        #pragma unroll
        for (int pass = 0; pass < 4; ++pass) {   // c = pass*64 + tid>>2 ; x4 = (tid&3)*4
            int c  = pass * 64 + (tid >> 2);
            int x4 = (tid & 3) * 4;
            float4 v = *(const float4*)(xp + (size_t)c * NPIX + x4);
            shm[(x4 + 0) * (CIN + 2) + c] = (ushort)bf16rne(v.x);
            shm[(x4 + 1) * (CIN + 2) + c] = (ushort)bf16rne(v.y);
            shm[(x4 + 2) * (CIN + 2) + c] = (ushort)bf16rne(v.z);
            shm[(x4 + 3) * (CIN + 2) + c] = (ushort)bf16rne(v.w);
        }
        __syncthreads();
        ushort* __restrict__ op = xt + (size_t)by * WW * CIN + (size_t)q * 16 * CIN;
        #pragma unroll
        for (int pass = 0; pass < 8; ++pass) {   // r = pass*2 + tid>>7 ; c2 = (tid&127)*2
            int r  = pass * 2 + (tid >> 7);
            int c2 = (tid & 127) * 2;
            uint v = (uint)shm[r * (CIN + 2) + c2] | ((uint)shm[r * (CIN + 2) + c2 + 1] << 16);
            *(uint*)(op + (size_t)r * CIN + c2) = v;
        }
    } else {
        // convert_w: one o per block
        const int o = bid - 2048;
        const float* __restrict__ wo = w + (size_t)o * CKTOT;
        #pragma unroll
        for (int m = 0; m < 9; ++m)
            shm[m * 256 + tid] = (ushort)bf16rne(wo[m * 256 + tid]);
        __syncthreads();
        ushort* __restrict__ op = wbf + (size_t)o * CKTOT;
        #pragma unroll
        for (int m = 0; m < 9; ++m) {
            int dst = m * 256 + tid;             // = kk*256 + c
            int kk = dst >> 8, c = dst & 255;
            op[dst] = shm[c * 9 + kk];
        }
    }
}

__device__ __forceinline__ uint4 combine4(uint4 c0, uint4 c1, uint4 c2, uint4 c3,
                                          float w0, float w1, float w2, float w3) {
    const uint u0[4] = {c0.x, c0.y, c0.z, c0.w};
    const uint u1[4] = {c1.x, c1.y, c1.z, c1.w};
    const uint u2[4] = {c2.x, c2.y, c2.z, c2.w};
    const uint u3[4] = {c3.x, c3.y, c3.z, c3.w};
    uint pk[4];
    #pragma unroll
    for (int q = 0; q < 4; ++q) {
        float slo = w0 * bflo(u0[q]) + w1 * bflo(u1[q]) + w2 * bflo(u2[q]) + w3 * bflo(u3[q]);
        float shi = w0 * bfhi(u0[q]) + w1 * bfhi(u1[q]) + w2 * bfhi(u2[q]) + w3 * bfhi(u3[q]);
        pk[q] = bf16rne(slo) | (bf16rne(shi) << 16);
    }
    return make_uint4(pk[0], pk[1], pk[2], pk[3]);
}

// ---- Kernel B: PB=16, 8 blocks/CU — TLP-first; immediate-combine gather + MFMA ----
__global__ __launch_bounds__(256) void align_conv(const ushort* __restrict__ xt,
                                                  const float* __restrict__ anchors,
                                                  const ushort* __restrict__ wbf,
                                                  float* __restrict__ out) {
    __shared__ uint4   smp[PB * ROWBLK];         // 10 KB
    __shared__ ushort4 midx[PB * K2];            // 1.125 KB
    __shared__ ushort4 mwh [PB * K2];            // 1.125 KB

    const int tid = threadIdx.x;
    const int bid = blockIdx.x;
    const int swz = (bid & 7) * 256 + (bid >> 3);   // 8 XCDs x 256 blocks: XCD owns one image
    const int g0  = swz * PB;
    const int b   = g0 >> 12;
    const int l0  = g0 & 4095;
    const int y   = l0 >> 6;
    const int xb0 = l0 & 63;                        // 0/16/32/48
    const ushort* __restrict__ xtb = xt + (size_t)b * NPIX * CIN;

    // ---- phase 0: bilinear metadata (16 pos x 9 taps = 144) ----
    if (tid < PB * K2) {
        int i = tid;
        int p = i / 9;
        int k = i - p * 9;
        const float* a = anchors + ((size_t)b * 4096 + l0 + p) * 5;
        float xc = a[0] * INV_STRIDE;
        float yc = a[1] * INV_STRIDE;
        float dw = (a[2] * INV_STRIDE) * (1.f / 3.f);
        float dh = (a[3] * INV_STRIDE) * (1.f / 3.f);
        float ang = a[4];
        float cs = cosf(ang), sn = sinf(ang);
        float kxf = (float)(k % 3 - 1);
        float kyf = (float)(k / 3 - 1);
        float xk = dw * kxf, yk = dh * kyf;
        float px = cs * xk - sn * yk + xc;
        float py = sn * xk + cs * yk + yc;

        float x0f = floorf(px), y0f = floorf(py);
        float wx1 = px - x0f,   wy1 = py - y0f;
        float wx0 = 1.f - wx1,  wy0 = 1.f - wy1;
        int x0 = (int)x0f, y0 = (int)y0f;
        int x1 = x0 + 1,   y1 = y0 + 1;
        bool vx0 = (x0 >= 0) & (x0 < WW);
        bool vx1 = (x1 >= 0) & (x1 < WW);
        bool vy0 = (y0 >= 0) & (y0 < HH);
        bool vy1 = (y1 >= 0) & (y1 < HH);
        int xc0 = min(max(x0, 0), WW - 1);
        int xc1 = min(max(x1, 0), WW - 1);
        int yc0 = min(max(y0, 0), HH - 1);
        int yc1 = min(max(y1, 0), HH - 1);
        float f0 = (vy0 & vx0) ? wy0 * wx0 : 0.f;
        float f1 = (vy0 & vx1) ? wy0 * wx1 : 0.f;
        float f2 = (vy1 & vx0) ? wy1 * wx0 : 0.f;
        float f3 = (vy1 & vx1) ? wy1 * wx1 : 0.f;
        midx[i] = make_ushort4((ushort)(yc0 * WW + xc0), (ushort)(yc0 * WW + xc1),
                               (ushort)(yc1 * WW + xc0), (ushort)(yc1 * WW + xc1));
        mwh[i]  = make_ushort4(__half_as_ushort(__float2half(f0)),
                               __half_as_ushort(__float2half(f1)),
                               __half_as_ushort(__float2half(f2)),
                               __half_as_ushort(__float2half(f3)));
    }

    const int lane = tid & 63;
    const int wn   = tid >> 6;       // 4 waves: output quarter (64 couts)
    const int lr   = lane & 15;
    const int kg   = lane >> 4;      // K-subgroup; also D row-quad (position quad)

    f32x4 acc[4];
    #pragma unroll
    for (int ni = 0; ni < 4; ++ni) acc[ni] = (f32x4){0.f, 0.f, 0.f, 0.f};

    // one staging task: load 4 corner bf16x8 rows, combine, write LDS (short live range)
    auto TASK = [&](int t, int ch) {
        int cb = t & 3;
        int pp = (t >> 2) & 15;
        int kk = t >> 6;                 // t in 0..575 -> kk 0..8
        int i  = pp * 9 + kk;
        ushort4 mi = midx[i];
        ushort4 mh = mwh[i];
        float w0 = __half2float(__ushort_as_half(mh.x));
        float w1 = __half2float(__ushort_as_half(mh.y));
        float w2 = __half2float(__ushort_as_half(mh.z));
        float w3 = __half2float(__ushort_as_half(mh.w));
        int ch0 = ch * CCH + cb * 8;
        uint4 c0 = *(const uint4*)(xtb + (size_t)mi.x * CIN + ch0);
        uint4 c1 = *(const uint4*)(xtb + (size_t)mi.y * CIN + ch0);
        uint4 c2 = *(const uint4*)(xtb + (size_t)mi.z * CIN + ch0);
        uint4 c3 = *(const uint4*)(xtb + (size_t)mi.w * CIN + ch0);
        smp[pp * ROWBLK + ((kk * 4 + cb) ^ (pp & 7))] =
            combine4(c0, c1, c2, c3, w0, w1, w2, w3);
    };

    auto STAGE = [&](int ch) {           // 576 tasks: 2 full passes + wave-0 tail
        TASK(tid, ch);
        TASK(tid + 256, ch);
        if (tid < 64) TASK(tid + 512, ch);
    };

    auto MFMA = [&](int ch) {
        const ushort* wbase = wbf + (size_t)(wn * 64 + lr) * CKTOT + ch * CCH + kg * 8;
        __builtin_amdgcn_s_setprio(1);
        #pragma unroll 3
        for (int kk = 0; kk < 9; ++kk) {
            int blk = kk * 4 + kg;
            Pack16 a0; a0.u = smp[lr * ROWBLK + (blk ^ (lr & 7))];
            const ushort* wk = wbase + kk * 256;
            bf16x8 b0 = *(const bf16x8*)(wk);
            bf16x8 b1 = *(const bf16x8*)(wk + 16 * CKTOT);
            bf16x8 b2 = *(const bf16x8*)(wk + 32 * CKTOT);
            bf16x8 b3 = *(const bf16x8*)(wk + 48 * CKTOT);
            acc[0] = __builtin_amdgcn_mfma_f32_16x16x32_bf16(a0.v, b0, acc[0], 0, 0, 0);
            acc[1] = __builtin_amdgcn_mfma_f32_16x16x32_bf16(a0.v, b1, acc[1], 0, 0, 0);
            acc[2] = __builtin_amdgcn_mfma_f32_16x16x32_bf16(a0.v, b2, acc[2], 0, 0, 0);
            acc[3] = __builtin_amdgcn_mfma_f32_16x16x32_bf16(a0.v, b3, acc[3], 0, 0, 0);
        }
        __builtin_amdgcn_s_setprio(0);
    };

    __syncthreads();                 // meta ready
    for (int ch = 0; ch < NCH; ++ch) {
        STAGE(ch);
        __syncthreads();             // smp(ch) ready
        MFMA(ch);
        __syncthreads();             // smp reads done
    }

    // ---- epilogue: relu + float4 stores (D: col=lr -> cout, row=kg*4+q -> position) ----
    const int xo = xb0 + kg * 4;
    #pragma unroll
    for (int ni = 0; ni < 4; ++ni) {
        int o = wn * 64 + ni * 16 + lr;
        float4 v;
        v.x = fmaxf(acc[ni][0], 0.f);
        v.y = fmaxf(acc[ni][1], 0.f);
        v.z = fmaxf(acc[ni][2], 0.f);
        v.w = fmaxf(acc[ni][3], 0.f);
        *(float4*)&out[(((size_t)b * COUT + o) * HH + y) * WW + xo] = v;
    }
}

extern "C" void kernel_launch(void* const* d_in, const int* in_sizes, int n_in,
                              void* d_out, int out_size, void* d_ws, size_t ws_size,
                              hipStream_t stream) {
    const float* x       = (const float*)d_in[0];
    const float* anchors = (const float*)d_in[1];
    const float* w       = (const float*)d_in[2];
    ushort* xt  = (ushort*)d_ws;                                            // 16 MB
    ushort* wbf = (ushort*)((char*)d_ws + (size_t)BATCH * NPIX * CIN * 2);  // 1.18 MB
    float* out  = (float*)d_out;

    hipLaunchKernelGGL(prep, dim3(2048 + COUT), dim3(256), 0, stream, x, w, xt, wbf);
    hipLaunchKernelGGL(align_conv, dim3((BATCH * HH * WW) / PB), dim3(256), 0, stream,
                       xt, anchors, wbf, out);
}

// Round 10
// 189.705 us; speedup vs baseline: 2.1134x; 2.1134x over previous
//
#include <hip/hip_runtime.h>
#include <hip/hip_fp16.h>
#include <math.h>

#define BATCH 8
#define CIN   256
#define COUT  256
#define HH    64
#define WW    64
#define K2    9
#define CKTOT 2304           // CIN*K2
#define NPIX  4096
#define MTOT  (BATCH*NPIX)   // 32768
#define INV_STRIDE 0.125f

typedef __attribute__((ext_vector_type(8))) short bf16x8;
typedef __attribute__((ext_vector_type(4))) float f32x4;
union Pack16 { uint4 u; bf16x8 v; };

__device__ __forceinline__ unsigned bf16rne(float f) {
    union { float f; unsigned u; } a; a.f = f;
    return (a.u + 0x7FFFu + ((a.u >> 16) & 1u)) >> 16;
}
__device__ __forceinline__ float bflo(unsigned u) {
    union { unsigned u; float f; } a; a.u = u << 16; return a.f;
}
__device__ __forceinline__ float bfhi(unsigned u) {
    union { unsigned u; float f; } a; a.u = u & 0xFFFF0000u; return a.f;
}

__device__ __forceinline__ uint4 combine4(uint4 c0, uint4 c1, uint4 c2, uint4 c3,
                                          float w0, float w1, float w2, float w3) {
    const uint u0[4] = {c0.x, c0.y, c0.z, c0.w};
    const uint u1[4] = {c1.x, c1.y, c1.z, c1.w};
    const uint u2[4] = {c2.x, c2.y, c2.z, c2.w};
    const uint u3[4] = {c3.x, c3.y, c3.z, c3.w};
    uint pk[4];
    #pragma unroll
    for (int q = 0; q < 4; ++q) {
        float slo = w0 * bflo(u0[q]) + w1 * bflo(u1[q]) + w2 * bflo(u2[q]) + w3 * bflo(u3[q]);
        float shi = w0 * bfhi(u0[q]) + w1 * bfhi(u1[q]) + w2 * bfhi(u2[q]) + w3 * bfhi(u3[q]);
        pk[q] = bf16rne(slo) | (bf16rne(shi) << 16);
    }
    return make_uint4(pk[0], pk[1], pk[2], pk[3]);
}

// ---- Kernel P: blocks [0,2048) transpose x quarter-rows to NHWC bf16;
//      [2048,2304) relayout w -> wbf[o][kk*256+c]; [2304,2432) meta table ----
__global__ __launch_bounds__(256) void prep(const float* __restrict__ x,
                                            const float* __restrict__ w,
                                            const float* __restrict__ anchors,
                                            ushort* __restrict__ xt,
                                            ushort* __restrict__ wbf,
                                            uint4*  __restrict__ mg) {
    __shared__ ushort shm[16 * (CIN + 2)];
    const int bid = blockIdx.x;
    const int tid = threadIdx.x;
    if (bid < 2048) {
        const int by = bid >> 2;
        const int q  = bid & 3;
        const float* __restrict__ xp = x + (size_t)(by >> 6) * CIN * NPIX
                                         + (size_t)(by & 63) * WW + q * 16;
        #pragma unroll
        for (int pass = 0; pass < 4; ++pass) {
            int c  = pass * 64 + (tid >> 2);
            int x4 = (tid & 3) * 4;
            float4 v = *(const float4*)(xp + (size_t)c * NPIX + x4);
            shm[(x4 + 0) * (CIN + 2) + c] = (ushort)bf16rne(v.x);
            shm[(x4 + 1) * (CIN + 2) + c] = (ushort)bf16rne(v.y);
            shm[(x4 + 2) * (CIN + 2) + c] = (ushort)bf16rne(v.z);
            shm[(x4 + 3) * (CIN + 2) + c] = (ushort)bf16rne(v.w);
        }
        __syncthreads();
        ushort* __restrict__ op = xt + (size_t)by * WW * CIN + (size_t)q * 16 * CIN;
        #pragma unroll
        for (int pass = 0; pass < 8; ++pass) {
            int r  = pass * 2 + (tid >> 7);
            int c2 = (tid & 127) * 2;
            uint v = (uint)shm[r * (CIN + 2) + c2] | ((uint)shm[r * (CIN + 2) + c2 + 1] << 16);
            *(uint*)(op + (size_t)r * CIN + c2) = v;
        }
    } else if (bid < 2304) {
        const int o = bid - 2048;
        const float* __restrict__ wo = w + (size_t)o * CKTOT;
        #pragma unroll
        for (int m = 0; m < 9; ++m)
            shm[m * 256 + tid] = (ushort)bf16rne(wo[m * 256 + tid]);
        __syncthreads();
        ushort* __restrict__ op = wbf + (size_t)o * CKTOT;
        #pragma unroll
        for (int m = 0; m < 9; ++m) {
            int dst = m * 256 + tid;
            int kk = dst >> 8, c = dst & 255;
            op[dst] = shm[c * 9 + kk];
        }
    } else {
        // meta: one thread per position bp; 9 taps each
        const int bp = (bid - 2304) * 256 + tid;   // 0..32767
        const float* a = anchors + (size_t)bp * 5;
        float xc = a[0] * INV_STRIDE;
        float yc = a[1] * INV_STRIDE;
        float dw = (a[2] * INV_STRIDE) * (1.f / 3.f);
        float dh = (a[3] * INV_STRIDE) * (1.f / 3.f);
        float cs = cosf(a[4]), sn = sinf(a[4]);
        uint4* __restrict__ mp = mg + (size_t)bp * 9;
        #pragma unroll
        for (int k = 0; k < 9; ++k) {
            float kxf = (float)(k % 3 - 1);
            float kyf = (float)(k / 3 - 1);
            float xk = dw * kxf, yk = dh * kyf;
            float px = cs * xk - sn * yk + xc;
            float py = sn * xk + cs * yk + yc;
            float x0f = floorf(px), y0f = floorf(py);
            float wx1 = px - x0f,   wy1 = py - y0f;
            float wx0 = 1.f - wx1,  wy0 = 1.f - wy1;
            int x0 = (int)x0f, y0 = (int)y0f;
            int x1 = x0 + 1,   y1 = y0 + 1;
            bool vx0 = (x0 >= 0) & (x0 < WW);
            bool vx1 = (x1 >= 0) & (x1 < WW);
            bool vy0 = (y0 >= 0) & (y0 < HH);
            bool vy1 = (y1 >= 0) & (y1 < HH);
            int xc0 = min(max(x0, 0), WW - 1);
            int xc1 = min(max(x1, 0), WW - 1);
            int yc0 = min(max(y0, 0), HH - 1);
            int yc1 = min(max(y1, 0), HH - 1);
            float f0 = (vy0 & vx0) ? wy0 * wx0 : 0.f;
            float f1 = (vy0 & vx1) ? wy0 * wx1 : 0.f;
            float f2 = (vy1 & vx0) ? wy1 * wx0 : 0.f;
            float f3 = (vy1 & vx1) ? wy1 * wx1 : 0.f;
            uint i0 = (uint)(yc0 * WW + xc0), i1 = (uint)(yc0 * WW + xc1);
            uint i2 = (uint)(yc1 * WW + xc0), i3 = (uint)(yc1 * WW + xc1);
            uint h01 = (uint)__half_as_ushort(__float2half(f0))
                     | ((uint)__half_as_ushort(__float2half(f1)) << 16);
            uint h23 = (uint)__half_as_ushort(__float2half(f2))
                     | ((uint)__half_as_ushort(__float2half(f3)) << 16);
            mp[k] = make_uint4(i0 | (i1 << 16), i2 | (i3 << 16), h01, h23);
        }
    }
}

// ---- Kernel G: barrier-free bilinear gather -> sm[mloc][kk*256+c] bf16 ----
__global__ __launch_bounds__(256) void gather(const ushort* __restrict__ xt,
                                              const uint4* __restrict__ mg,
                                              ushort* __restrict__ sm,
                                              int m0, int mrows) {
    const long ntask = (long)mrows * 288;            // (m, kk, cb) ; cb = 8-ch block
    const int  nb    = gridDim.x;
    const int  vbid  = (blockIdx.x & 7) * (nb >> 3) + (blockIdx.x >> 3); // XCD-chunked
    const long per   = (ntask + nb - 1) / nb;
    const long t0    = (long)vbid * per;
    const long t1    = (t0 + per < ntask) ? t0 + per : ntask;
    for (long t = t0 + threadIdx.x; t < t1; t += 256) {
        int  cb   = (int)t & 31;
        uint mk   = (uint)(t >> 5);
        uint mloc = mk / 9u;
        int  kk   = (int)(mk - mloc * 9u);
        int  mglob = m0 + (int)mloc;
        uint4 mt = mg[(size_t)mglob * 9 + kk];
        const ushort* base = xt + ((size_t)(mglob & ~4095)) * CIN + cb * 8;
        float w0 = __half2float(__ushort_as_half((ushort)(mt.z & 0xffff)));
        float w1 = __half2float(__ushort_as_half((ushort)(mt.z >> 16)));
        float w2 = __half2float(__ushort_as_half((ushort)(mt.w & 0xffff)));
        float w3 = __half2float(__ushort_as_half((ushort)(mt.w >> 16)));
        uint4 c0 = *(const uint4*)(base + (size_t)(mt.x & 0xffff) * CIN);
        uint4 c1 = *(const uint4*)(base + (size_t)(mt.x >> 16)    * CIN);
        uint4 c2 = *(const uint4*)(base + (size_t)(mt.y & 0xffff) * CIN);
        uint4 c3 = *(const uint4*)(base + (size_t)(mt.y >> 16)    * CIN);
        *(uint4*)(sm + (size_t)mloc * CKTOT + kk * 256 + cb * 8) =
            combine4(c0, c1, c2, c3, w0, w1, w2, w3);
    }
}

// ---- Kernel M: A(sm)·B(wbf)^T GEMM, 128x128 tile, BK=64, dbuf LDS, XOR-swizzle ----
__global__ __launch_bounds__(256) void gemm(const ushort* __restrict__ sm,
                                            const ushort* __restrict__ wbf,
                                            float* __restrict__ out,
                                            int m0) {
    __shared__ ushort sA[2][128 * 64];   // 32 KB  [buf][row*64 + perm-k]
    __shared__ ushort sB[2][128 * 64];   // 32 KB

    const int tid  = threadIdx.x;
    const int bx   = blockIdx.x;         // M-tile within group
    const int by   = blockIdx.y;         // N half (128 couts)
    const int lane = tid & 63, wid = tid >> 6;
    const int wm   = wid >> 1, wn = wid & 1;   // 2x2 waves, 64x64 each
    const int lr   = lane & 15, kg = lane >> 4;
    const int mbase = bx * 128;

    f32x4 acc[4][4];
    #pragma unroll
    for (int mf = 0; mf < 4; ++mf)
        #pragma unroll
        for (int nf = 0; nf < 4; ++nf)
            acc[mf][nf] = (f32x4){0.f, 0.f, 0.f, 0.f};

    // stage one 128x64 K-slab of A and B (reg-staged, both-sides XOR swizzle)
    auto STAGE = [&](int cur, int t64) {
        const int k0 = t64 * 64;
        #pragma unroll
        for (int j = 0; j < 4; ++j) {
            int g   = tid + j * 256;       // 16B-block id: row*8 + blk
            int row = g >> 3;
            int blk = g & 7;
            int dst = row * 64 + ((blk ^ (row & 7)) * 8);
            uint4 va = *(const uint4*)(sm  + (size_t)(mbase + row) * CKTOT + k0 + blk * 8);
            uint4 vb = *(const uint4*)(wbf + (size_t)(by * 128 + row) * CKTOT + k0 + blk * 8);
            *(uint4*)&sA[cur][dst] = va;
            *(uint4*)&sB[cur][dst] = vb;
        }
    };

    auto COMPUTE = [&](int cur) {
        #pragma unroll
        for (int ks = 0; ks < 2; ++ks) {
            Pack16 af[4], bfr[4];
            #pragma unroll
            for (int mf = 0; mf < 4; ++mf) {
                int row = wm * 64 + mf * 16 + lr;
                af[mf].u = *(const uint4*)&sA[cur][row * 64 + (((ks * 4 + kg) ^ (row & 7)) * 8)];
            }
            #pragma unroll
            for (int nf = 0; nf < 4; ++nf) {
                int row = wn * 64 + nf * 16 + lr;
                bfr[nf].u = *(const uint4*)&sB[cur][row * 64 + (((ks * 4 + kg) ^ (row & 7)) * 8)];
            }
            #pragma unroll
            for (int mf = 0; mf < 4; ++mf)
                #pragma unroll
                for (int nf = 0; nf < 4; ++nf)
                    acc[mf][nf] = __builtin_amdgcn_mfma_f32_16x16x32_bf16(
                        af[mf].v, bfr[nf].v, acc[mf][nf], 0, 0, 0);
        }
    };

    STAGE(0, 0);
    __syncthreads();
    int cur = 0;
    for (int t = 0; t < 36; ++t) {
        if (t + 1 < 36) STAGE(cur ^ 1, t + 1);
        COMPUTE(cur);
        __syncthreads();        // next buf staged; this buf's reads done
        cur ^= 1;
    }

    // epilogue: relu + float4 stores to NCHW
    const int mg0 = m0 + mbase + wm * 64;
    #pragma unroll
    for (int mf = 0; mf < 4; ++mf) {
        int mglob = mg0 + mf * 16 + kg * 4;
        int b = mglob >> 12;
        int p = mglob & 4095;
        #pragma unroll
        for (int nf = 0; nf < 4; ++nf) {
            int o = by * 128 + wn * 64 + nf * 16 + lr;
            float4 v;
            v.x = fmaxf(acc[mf][nf][0], 0.f);
            v.y = fmaxf(acc[mf][nf][1], 0.f);
            v.z = fmaxf(acc[mf][nf][2], 0.f);
            v.w = fmaxf(acc[mf][nf][3], 0.f);
            *(float4*)&out[((size_t)(b * COUT + o)) * NPIX + p] = v;
        }
    }
}

extern "C" void kernel_launch(void* const* d_in, const int* in_sizes, int n_in,
                              void* d_out, int out_size, void* d_ws, size_t ws_size,
                              hipStream_t stream) {
    const float* x       = (const float*)d_in[0];
    const float* anchors = (const float*)d_in[1];
    const float* w       = (const float*)d_in[2];
    float* out = (float*)d_out;

    const size_t XT  = (size_t)BATCH * NPIX * CIN * 2;   // 16.78 MB
    const size_t WBF = (size_t)COUT * CKTOT * 2;         // 1.18 MB
    const size_t MGS = (size_t)MTOT * 9 * 16;            // 4.72 MB
    char* base = (char*)d_ws;
    ushort* xt  = (ushort*)base;
    ushort* wbf = (ushort*)(base + XT);
    uint4*  mg  = (uint4*)(base + XT + WBF);
    ushort* sm  = (ushort*)(base + XT + WBF + MGS);

    // sample-group rows sized to workspace (deterministic -> graph-safe)
    long maxrows = 0;
    if (ws_size > XT + WBF + MGS)
        maxrows = (long)((ws_size - XT - WBF - MGS) / ((size_t)CKTOT * 2));
    maxrows = (maxrows / 128) * 128;
    if (maxrows > MTOT) maxrows = MTOT;
    if (maxrows < 128)  maxrows = 128;   // assume ws is at least modest

    hipLaunchKernelGGL(prep, dim3(2048 + 256 + 128), dim3(256), 0, stream,
                       x, w, anchors, xt, wbf, mg);

    for (long done = 0; done < MTOT; ) {
        long g = MTOT - done;
        if (g > maxrows) g = maxrows;
        hipLaunchKernelGGL(gather, dim3(2048), dim3(256), 0, stream,
                           xt, mg, sm, (int)done, (int)g);
        hipLaunchKernelGGL(gemm, dim3((unsigned)(g / 128), 2), dim3(256), 0, stream,
                           sm, wbf, out, (int)done);
        done += g;
    }
}